// Round 3
// baseline (1657.005 us; speedup 1.0000x reference)
//
#include <hip/hip_runtime.h>
#include <math.h>

#define NN 100000
#define BSZ 256                    // nodes per bucket
#define NB 391                     // ceil(NN/BSZ)
#define NB2 782                    // both halves
constexpr float MAXNORM_C = 0.996f;   // (1 - 4e-3)/sqrt(c), c=1
constexpr float MINNORM_C = 1e-15f;

// ---------- prep: transpose the 4 weight matrices into ws ----------
__global__ void prep_transpose(const float* __restrict__ Wp, const float* __restrict__ Wpc,
                               const float* __restrict__ Wn, const float* __restrict__ Wnc,
                               float* __restrict__ wt) {
    int idx = blockIdx.x * 256 + threadIdx.x;   // 0..16383
    int m = idx >> 12;
    int k = (idx >> 6) & 63;
    int j = idx & 63;
    const float* W = (m == 0) ? Wp : (m == 1) ? Wpc : (m == 2) ? Wn : Wnc;
    wt[idx] = W[j * 64 + k];
}

__device__ inline float wave_sum64(float v) {
    #pragma unroll
    for (int m = 32; m >= 1; m >>= 1) v += __shfl_xor(v, m, 64);
    return v;
}

// ---------- prep: hyp_bias = proj(expmap0(b, c), c), plus its |.|^2 ----------
__global__ void prep_bias(const float* __restrict__ bp, const float* __restrict__ bn,
                          float* __restrict__ hb) {
    int l = threadIdx.x;   // one wave
    #pragma unroll
    for (int h = 0; h < 2; ++h) {
        float u = (h ? bn : bp)[l];
        float norm = fmaxf(sqrtf(wave_sum64(u * u)), MINNORM_C);
        float s = tanhf(norm) / norm;          // sqrt_c = 1
        float v = s * u;
        float vn = fmaxf(sqrtf(wave_sum64(v * v)), MINNORM_C);
        if (vn > MAXNORM_C) v *= MAXNORM_C / vn;
        float y2 = wave_sum64(v * v);
        hb[h * 65 + l] = v;
        if (l == 0) hb[h * 65 + 64] = y2;
    }
}

// ---------- bucket count: per-block LDS histogram -> global atomics ----------
__global__ __launch_bounds__(256) void bucket_count(
    const int* __restrict__ pei, int E1,
    const int* __restrict__ nei, int E2,
    int* __restrict__ gcnt) {
    __shared__ int h[NB2];
    int tid = threadIdx.x;
    for (int i = tid; i < NB2; i += 256) h[i] = 0;
    __syncthreads();
    int tot = E1 + E2;
    int base = blockIdx.x * 8192;
    #pragma unroll 4
    for (int k = 0; k < 32; ++k) {
        int idx = base + k * 256 + tid;
        if (idx < tot) {
            int half = idx >= E1;
            int e = idx - (half ? E1 : 0);
            const int* ei = half ? nei : pei;
            int E = half ? E2 : E1;
            int dst = ei[E + e];
            atomicAdd(&h[half * NB + (dst >> 8)], 1);
        }
    }
    __syncthreads();
    for (int i = tid; i < NB2; i += 256) {
        int c = h[i];
        if (c) atomicAdd(&gcnt[i], c);
    }
}

// ---------- exclusive scan of NB2 bucket counts (single block) ----------
__global__ void bucket_scan(const int* __restrict__ gcnt, int* __restrict__ goffs,
                            int* __restrict__ gcursor) {
    __shared__ int tmp[256];
    int tid = threadIdx.x;
    int base = tid * 4;
    int items[4];
    int s = 0;
    #pragma unroll
    for (int i = 0; i < 4; ++i) {
        items[i] = (base + i < NB2) ? gcnt[base + i] : 0;
        s += items[i];
    }
    tmp[tid] = s;
    __syncthreads();
    for (int off = 1; off < 256; off <<= 1) {
        int v = (tid >= off) ? tmp[tid - off] : 0;
        __syncthreads();
        tmp[tid] += v;
        __syncthreads();
    }
    int run = tmp[tid] - s;
    #pragma unroll
    for (int i = 0; i < 4; ++i) {
        if (base + i < NB2) { goffs[base + i] = run; gcursor[base + i] = run; }
        run += items[i];
    }
}

// ---------- bucket scatter: two-pass block aggregation, packed writes ----------
// packed edge = (src << 8) | (dst & 255)   (src < 2^17, fits 25 bits)
__global__ __launch_bounds__(256) void bucket_scatter(
    const int* __restrict__ pei, int E1,
    const int* __restrict__ nei, int E2,
    int* __restrict__ gcursor, int* __restrict__ packed) {
    __shared__ int h[NB2];
    __shared__ int hb[NB2];
    int tid = threadIdx.x;
    for (int i = tid; i < NB2; i += 256) h[i] = 0;
    __syncthreads();
    int tot = E1 + E2;
    int base = blockIdx.x * 8192;
    // pass A: histogram
    #pragma unroll 4
    for (int k = 0; k < 32; ++k) {
        int idx = base + k * 256 + tid;
        if (idx < tot) {
            int half = idx >= E1;
            int e = idx - (half ? E1 : 0);
            const int* ei = half ? nei : pei;
            int E = half ? E2 : E1;
            int dst = ei[E + e];
            atomicAdd(&h[half * NB + (dst >> 8)], 1);
        }
    }
    __syncthreads();
    // reserve chunks
    for (int i = tid; i < NB2; i += 256) {
        int c = h[i];
        hb[i] = c ? atomicAdd(&gcursor[i], c) : 0;
    }
    __syncthreads();
    for (int i = tid; i < NB2; i += 256) h[i] = 0;
    __syncthreads();
    // pass B: claim local rank, write packed
    #pragma unroll 4
    for (int k = 0; k < 32; ++k) {
        int idx = base + k * 256 + tid;
        if (idx < tot) {
            int half = idx >= E1;
            int e = idx - (half ? E1 : 0);
            const int* ei = half ? nei : pei;
            int E = half ? E2 : E1;
            int src = ei[e];
            int dst = ei[E + e];
            int b = half * NB + (dst >> 8);
            int r = atomicAdd(&h[b], 1);
            packed[hb[b] + r] = (src << 8) | (dst & 255);
        }
    }
}

// ---------- bucket gather: one block per bucket, LDS accumulator ----------
__global__ __launch_bounds__(512) void bucket_gather(
    const int* __restrict__ goffs, const int* __restrict__ gcnt,
    const int* __restrict__ packed, const float* __restrict__ x,
    float* __restrict__ out) {
    __shared__ float acc[BSZ * 64];   // 64 KB
    __shared__ float dcnt[BSZ];
    int tid = threadIdx.x;
    int w = tid >> 6;
    int lane = tid & 63;
    float4* a4 = (float4*)acc;
    for (int i = tid; i < BSZ * 16; i += 512) a4[i] = make_float4(0.f, 0.f, 0.f, 0.f);
    if (tid < BSZ) dcnt[tid] = 0.f;
    __syncthreads();

    int bucket = blockIdx.x;
    int half = bucket >= NB;
    int b0 = (bucket - (half ? NB : 0)) * BSZ;   // node base
    int start = goffs[bucket];
    int end = start + gcnt[bucket];

    for (int i = start + w * 4; i < end; i += 32) {
        int m = end - i;
        if (m >= 4) {
            int p0 = packed[i], p1 = packed[i + 1], p2 = packed[i + 2], p3 = packed[i + 3];
            float v0 = x[(p0 >> 8) * 64 + lane];
            float v1 = x[(p1 >> 8) * 64 + lane];
            float v2 = x[(p2 >> 8) * 64 + lane];
            float v3 = x[(p3 >> 8) * 64 + lane];
            atomicAdd(&acc[(p0 & 255) * 64 + lane], v0);
            atomicAdd(&acc[(p1 & 255) * 64 + lane], v1);
            atomicAdd(&acc[(p2 & 255) * 64 + lane], v2);
            atomicAdd(&acc[(p3 & 255) * 64 + lane], v3);
            if (lane < 4) {     // 4 counts in ONE ds_add instruction
                int ps = (lane == 0) ? p0 : (lane == 1) ? p1 : (lane == 2) ? p2 : p3;
                atomicAdd(&dcnt[ps & 255], 1.0f);
            }
        } else {
            for (int j = 0; j < m; ++j) {
                int p = packed[i + j];
                float v = x[(p >> 8) * 64 + lane];
                atomicAdd(&acc[(p & 255) * 64 + lane], v);
                if (lane == 0) atomicAdd(&dcnt[p & 255], 1.0f);
            }
        }
    }
    __syncthreads();

    // write means: wave w covers nodes w*32 .. w*32+31
    for (int n = w * 32; n < w * 32 + 32; ++n) {
        int node = b0 + n;
        if (node < NN) {
            float mval = acc[n * 64 + lane] / fmaxf(dcnt[n], 1.f);
            out[(size_t)node * 128 + half * 64 + lane] = mval;
        }
    }
}

// ---------- per-lane hyperbolic linear: proj(mobius_matvec(W, v, c)) ----------
__device__ inline void hyp_mm_proj(const float* vp, float cinv,
                                   const float* __restrict__ wtm, float (&mx)[64]) {
    #pragma unroll
    for (int j = 0; j < 64; ++j) mx[j] = 0.f;
    float vn2 = 0.f;
    for (int k0 = 0; k0 < 64; k0 += 4) {
        float4 a4 = *(const float4*)(vp + k0);
        float a0 = a4.x * cinv, a1 = a4.y * cinv, a2 = a4.z * cinv, a3 = a4.w * cinv;
        vn2 = fmaf(a0, a0, fmaf(a1, a1, fmaf(a2, a2, fmaf(a3, a3, vn2))));
        const float* w0 = wtm + k0 * 64;        // uniform address -> s_load
        #pragma unroll
        for (int j = 0; j < 64; ++j) {
            float m = mx[j];
            m = fmaf(a0, w0[j],        m);
            m = fmaf(a1, w0[64 + j],   m);
            m = fmaf(a2, w0[128 + j],  m);
            m = fmaf(a3, w0[192 + j],  m);
            mx[j] = m;
        }
    }
    float mn2 = 0.f;
    #pragma unroll
    for (int j = 0; j < 64; ++j) mn2 = fmaf(mx[j], mx[j], mn2);
    float xnorm = fmaxf(sqrtf(vn2), MINNORM_C);
    float mnorm = fmaxf(sqrtf(mn2), MINNORM_C);
    float z = fminf(xnorm, 1.0f - 1e-7f);                   // artanh clip
    float art = 0.5f * logf((1.0f + z) / (1.0f - z));
    float t = tanhf(mnorm / xnorm * art);
    float scale = (mn2 == 0.f) ? 0.f : (t / mnorm);         // zero_mx branch
    #pragma unroll
    for (int j = 0; j < 64; ++j) mx[j] *= scale;
    float rn2 = 0.f;
    #pragma unroll
    for (int j = 0; j < 64; ++j) rn2 = fmaf(mx[j], mx[j], rn2);
    float rnorm = fmaxf(sqrtf(rn2), MINNORM_C);
    float f = (rnorm > MAXNORM_C) ? (MAXNORM_C / rnorm) : 1.0f;   // proj
    #pragma unroll
    for (int j = 0; j < 64; ++j) mx[j] *= f;
}

// ---------- finalize: lane-per-node, one half per block ----------
__global__ __launch_bounds__(256) void finalize_kernel(
    const float* __restrict__ x,
    const float* __restrict__ wt,    // 4 transposed 64x64 matrices
    const float* __restrict__ hb,    // 2 x 65
    float* __restrict__ out) {
    int half = blockIdx.x & 1;                      // uniform -> scalar weight loads
    int group = (blockIdx.x >> 1) * 4 + (threadIdx.x >> 6);
    int lane = threadIdx.x & 63;
    int node = group * 64 + lane;
    bool valid = node < NN;
    int nc = valid ? node : NN - 1;

    const float* wtA = wt + half * 8192;            // W_pos / W_neg
    const float* wtB = wtA + 4096;                  // W_pos_cc / W_neg_cc
    const float* hbh = hb + half * 65;

    // chain A: proj(mobius_matvec(W, agg))  (agg = mean already, in out-half)
    float resA[64];
    hyp_mm_proj(out + (size_t)nc * 128 + half * 64, 1.0f, wtA, resA);

    // chain B: proj(mobius_matvec(W_cc, x))
    float resB[64];
    hyp_mm_proj(x + (size_t)nc * 64, 1.0f, wtB, resB);

    // proj(mobius_add(resB, hyp_bias)), c=1
    float x2 = 0.f, xy = 0.f;
    #pragma unroll
    for (int j = 0; j < 64; ++j) {
        x2 = fmaf(resB[j], resB[j], x2);
        xy = fmaf(resB[j], hbh[j], xy);
    }
    float y2 = hbh[64];
    float A = 1.f + 2.f * xy + y2;
    float B = 1.f - x2;
    float den = 1.f + 2.f * xy + x2 * y2;
    float dinv = 1.f / fmaxf(den, MINNORM_C);
    float rn2 = 0.f;
    #pragma unroll
    for (int j = 0; j < 64; ++j) {
        float r = (A * resB[j] + B * hbh[j]) * dinv;
        resB[j] = r;
        rn2 = fmaf(r, r, rn2);
    }
    float rnorm = fmaxf(sqrtf(rn2), MINNORM_C);
    float f = (rnorm > MAXNORM_C) ? (MAXNORM_C / rnorm) : 1.0f;

    if (valid) {
        float* op = out + (size_t)node * 128 + half * 64;
        #pragma unroll
        for (int k0 = 0; k0 < 64; k0 += 4) {
            float4 s;
            s.x = resA[k0 + 0] + resB[k0 + 0] * f;
            s.y = resA[k0 + 1] + resB[k0 + 1] * f;
            s.z = resA[k0 + 2] + resB[k0 + 2] * f;
            s.w = resA[k0 + 3] + resB[k0 + 3] * f;
            *(float4*)(op + k0) = s;
        }
    }
}

extern "C" void kernel_launch(void* const* d_in, const int* in_sizes, int n_in,
                              void* d_out, int out_size, void* d_ws, size_t ws_size,
                              hipStream_t stream) {
    const float* x   = (const float*)d_in[0];
    const float* Wp  = (const float*)d_in[1];
    const float* Wpc = (const float*)d_in[2];
    const float* bp  = (const float*)d_in[3];
    const float* Wn  = (const float*)d_in[4];
    const float* Wnc = (const float*)d_in[5];
    const float* bn  = (const float*)d_in[6];
    const int* pei = (const int*)d_in[7];
    const int* nei = (const int*)d_in[8];
    float* out = (float*)d_out;

    int E1 = in_sizes[7] / 2;
    int E2 = in_sizes[8] / 2;
    int tot = E1 + E2;

    // ws layout (4-byte units):
    //   gcnt[NB2] | goffs[NB2] | gcursor[NB2] | pad | hb[130+pad] | wt[16384] | packed[tot]
    int*   gcnt    = (int*)d_ws;
    int*   goffs   = gcnt + NB2;
    int*   gcursor = goffs + NB2;
    float* hbp     = (float*)(gcursor + NB2 + 2);    // align
    float* wt      = hbp + 192;
    int*   packed  = (int*)(wt + 16384);

    hipMemsetAsync(gcnt, 0, NB2 * sizeof(int), stream);

    prep_transpose<<<64, 256, 0, stream>>>(Wp, Wpc, Wn, Wnc, wt);
    prep_bias<<<1, 64, 0, stream>>>(bp, bn, hbp);

    int nblk = (tot + 8191) / 8192;    // 391
    bucket_count<<<nblk, 256, 0, stream>>>(pei, E1, nei, E2, gcnt);
    bucket_scan<<<1, 256, 0, stream>>>(gcnt, goffs, gcursor);
    bucket_scatter<<<nblk, 256, 0, stream>>>(pei, E1, nei, E2, gcursor, packed);
    bucket_gather<<<NB2, 512, 0, stream>>>(goffs, gcnt, packed, x, out);

    int groups = (NN + 63) / 64;                 // 1563
    int blocks = 2 * ((groups + 3) / 4);
    finalize_kernel<<<blocks, 256, 0, stream>>>(x, wt, hbp, out);
}

// Round 4
// 402.896 us; speedup vs baseline: 4.1127x; 4.1127x over previous
//
#include <hip/hip_runtime.h>
#include <math.h>

#define NN 100000
#define BSZ 256                    // nodes per bucket
#define NB 391                     // ceil(NN/BSZ)
#define NB2 782                    // both halves
constexpr float MAXNORM_C = 0.996f;   // (1 - 4e-3)/sqrt(c), c=1
constexpr float MINNORM_C = 1e-15f;

// ---------- prep: transpose the 4 weight matrices into ws ----------
__global__ void prep_transpose(const float* __restrict__ Wp, const float* __restrict__ Wpc,
                               const float* __restrict__ Wn, const float* __restrict__ Wnc,
                               float* __restrict__ wt) {
    int idx = blockIdx.x * 256 + threadIdx.x;   // 0..16383
    int m = idx >> 12;
    int k = (idx >> 6) & 63;
    int j = idx & 63;
    const float* W = (m == 0) ? Wp : (m == 1) ? Wpc : (m == 2) ? Wn : Wnc;
    wt[idx] = W[j * 64 + k];
}

__device__ inline float wave_sum64(float v) {
    #pragma unroll
    for (int m = 32; m >= 1; m >>= 1) v += __shfl_xor(v, m, 64);
    return v;
}

// ---------- prep: hyp_bias = proj(expmap0(b, c), c), plus its |.|^2 ----------
__global__ void prep_bias(const float* __restrict__ bp, const float* __restrict__ bn,
                          float* __restrict__ hb) {
    int l = threadIdx.x;   // one wave
    #pragma unroll
    for (int h = 0; h < 2; ++h) {
        float u = (h ? bn : bp)[l];
        float norm = fmaxf(sqrtf(wave_sum64(u * u)), MINNORM_C);
        float s = tanhf(norm) / norm;          // sqrt_c = 1
        float v = s * u;
        float vn = fmaxf(sqrtf(wave_sum64(v * v)), MINNORM_C);
        if (vn > MAXNORM_C) v *= MAXNORM_C / vn;
        float y2 = wave_sum64(v * v);
        hb[h * 65 + l] = v;
        if (l == 0) hb[h * 65 + 64] = y2;
    }
}

// ---------- bucket count: per-block LDS histogram -> global atomics ----------
__global__ __launch_bounds__(256) void bucket_count(
    const int* __restrict__ pei, int E1,
    const int* __restrict__ nei, int E2,
    int* __restrict__ gcnt) {
    __shared__ int h[NB2];
    int tid = threadIdx.x;
    for (int i = tid; i < NB2; i += 256) h[i] = 0;
    __syncthreads();
    int tot = E1 + E2;
    int base = blockIdx.x * 8192;
    #pragma unroll 4
    for (int k = 0; k < 32; ++k) {
        int idx = base + k * 256 + tid;
        if (idx < tot) {
            int half = idx >= E1;
            int e = idx - (half ? E1 : 0);
            const int* ei = half ? nei : pei;
            int E = half ? E2 : E1;
            int dst = ei[E + e];
            atomicAdd(&h[half * NB + (dst >> 8)], 1);
        }
    }
    __syncthreads();
    for (int i = tid; i < NB2; i += 256) {
        int c = h[i];
        if (c) atomicAdd(&gcnt[i], c);
    }
}

// ---------- exclusive scan of NB2 bucket counts (single block) ----------
__global__ void bucket_scan(const int* __restrict__ gcnt, int* __restrict__ goffs,
                            int* __restrict__ gcursor) {
    __shared__ int tmp[256];
    int tid = threadIdx.x;
    int base = tid * 4;
    int items[4];
    int s = 0;
    #pragma unroll
    for (int i = 0; i < 4; ++i) {
        items[i] = (base + i < NB2) ? gcnt[base + i] : 0;
        s += items[i];
    }
    tmp[tid] = s;
    __syncthreads();
    for (int off = 1; off < 256; off <<= 1) {
        int v = (tid >= off) ? tmp[tid - off] : 0;
        __syncthreads();
        tmp[tid] += v;
        __syncthreads();
    }
    int run = tmp[tid] - s;
    #pragma unroll
    for (int i = 0; i < 4; ++i) {
        if (base + i < NB2) { goffs[base + i] = run; gcursor[base + i] = run; }
        run += items[i];
    }
}

// ---------- bucket scatter: two-pass block aggregation, packed writes ----------
// packed edge = (src << 8) | (dst & 255)   (src < 2^17, fits 25 bits)
__global__ __launch_bounds__(256) void bucket_scatter(
    const int* __restrict__ pei, int E1,
    const int* __restrict__ nei, int E2,
    int* __restrict__ gcursor, int* __restrict__ packed) {
    __shared__ int h[NB2];
    __shared__ int hb[NB2];
    int tid = threadIdx.x;
    for (int i = tid; i < NB2; i += 256) h[i] = 0;
    __syncthreads();
    int tot = E1 + E2;
    int base = blockIdx.x * 8192;
    // pass A: histogram
    #pragma unroll 4
    for (int k = 0; k < 32; ++k) {
        int idx = base + k * 256 + tid;
        if (idx < tot) {
            int half = idx >= E1;
            int e = idx - (half ? E1 : 0);
            const int* ei = half ? nei : pei;
            int E = half ? E2 : E1;
            int dst = ei[E + e];
            atomicAdd(&h[half * NB + (dst >> 8)], 1);
        }
    }
    __syncthreads();
    // reserve chunks
    for (int i = tid; i < NB2; i += 256) {
        int c = h[i];
        hb[i] = c ? atomicAdd(&gcursor[i], c) : 0;
    }
    __syncthreads();
    for (int i = tid; i < NB2; i += 256) h[i] = 0;
    __syncthreads();
    // pass B: claim local rank, write packed
    #pragma unroll 4
    for (int k = 0; k < 32; ++k) {
        int idx = base + k * 256 + tid;
        if (idx < tot) {
            int half = idx >= E1;
            int e = idx - (half ? E1 : 0);
            const int* ei = half ? nei : pei;
            int E = half ? E2 : E1;
            int src = ei[e];
            int dst = ei[E + e];
            int b = half * NB + (dst >> 8);
            int r = atomicAdd(&h[b], 1);
            packed[hb[b] + r] = (src << 8) | (dst & 255);
        }
    }
}

// ---------- node sort: one block per bucket; sort edges to node order ----------
// Output: esrc (node-grouped src list), ndeg / noffs per node-half.
// All writes land in the bucket's own contiguous ~16 KB window -> L2-merged.
__global__ __launch_bounds__(256) void node_sort(
    const int* __restrict__ goffs, const int* __restrict__ gcnt,
    const int* __restrict__ packed,
    int* __restrict__ esrc, int* __restrict__ ndeg, int* __restrict__ noffs) {
    __shared__ int h[256];
    __shared__ int sc[256];
    int tid = threadIdx.x;
    int bucket = blockIdx.x;
    int start = goffs[bucket];
    int cnt = gcnt[bucket];
    h[tid] = 0;
    __syncthreads();
    for (int i = start + tid; i < start + cnt; i += 256)
        atomicAdd(&h[packed[i] & 255], 1);
    __syncthreads();
    int deg = h[tid];
    // exclusive scan of degrees
    sc[tid] = deg;
    __syncthreads();
    for (int off = 1; off < 256; off <<= 1) {
        int v = (tid >= off) ? sc[tid - off] : 0;
        __syncthreads();
        sc[tid] += v;
        __syncthreads();
    }
    int excl = sc[tid] - deg;
    int half = bucket >= NB;
    int node = (bucket - (half ? NB : 0)) * BSZ + tid;
    if (node < NN) {
        ndeg[half * NN + node] = deg;
        noffs[half * NN + node] = start + excl;
    }
    // reuse h as local cursor
    h[tid] = excl;
    __syncthreads();
    for (int i = start + tid; i < start + cnt; i += 256) {
        int p = packed[i];
        int r = atomicAdd(&h[p & 255], 1);
        esrc[start + r] = p >> 8;
    }
}

// ---------- gather: wave per node-half (high TLP), writes MEAN ----------
__global__ __launch_bounds__(256) void gather_kernel(
    const int* __restrict__ noffs, const int* __restrict__ ndeg,
    const int* __restrict__ esrc, const float* __restrict__ x,
    float* __restrict__ out) {
    int wid = (blockIdx.x * 256 + threadIdx.x) >> 6;   // node-half id, 0..2NN
    int lane = threadIdx.x & 63;
    if (wid >= 2 * NN) return;
    int half = wid >= NN;
    int node = wid - (half ? NN : 0);
    int start = noffs[wid];
    int deg = ndeg[wid];
    float acc = 0.f;
    for (int b = 0; b < deg; b += 64) {
        int n = min(64, deg - b);
        int s_l = (b + lane < deg) ? esrc[start + b + lane] : 0;
        int i = 0;
        for (; i + 4 <= n; i += 4) {
            int a0 = __shfl(s_l, i, 64), a1 = __shfl(s_l, i + 1, 64);
            int a2 = __shfl(s_l, i + 2, 64), a3 = __shfl(s_l, i + 3, 64);
            float v0 = x[a0 * 64 + lane], v1 = x[a1 * 64 + lane];
            float v2 = x[a2 * 64 + lane], v3 = x[a3 * 64 + lane];
            acc += (v0 + v1) + (v2 + v3);
        }
        for (; i < n; ++i) acc += x[__shfl(s_l, i, 64) * 64 + lane];
    }
    float m = acc / fmaxf((float)deg, 1.f);
    out[(size_t)node * 128 + half * 64 + lane] = m;
}

// ---------- per-lane hyperbolic linear: proj(mobius_matvec(W, v, c)) ----------
__device__ inline void hyp_mm_proj(const float* vp, float cinv,
                                   const float* __restrict__ wtm, float (&mx)[64]) {
    #pragma unroll
    for (int j = 0; j < 64; ++j) mx[j] = 0.f;
    float vn2 = 0.f;
    for (int k0 = 0; k0 < 64; k0 += 4) {
        float4 a4 = *(const float4*)(vp + k0);
        float a0 = a4.x * cinv, a1 = a4.y * cinv, a2 = a4.z * cinv, a3 = a4.w * cinv;
        vn2 = fmaf(a0, a0, fmaf(a1, a1, fmaf(a2, a2, fmaf(a3, a3, vn2))));
        const float* w0 = wtm + k0 * 64;        // uniform address -> s_load
        #pragma unroll
        for (int j = 0; j < 64; ++j) {
            float m = mx[j];
            m = fmaf(a0, w0[j],        m);
            m = fmaf(a1, w0[64 + j],   m);
            m = fmaf(a2, w0[128 + j],  m);
            m = fmaf(a3, w0[192 + j],  m);
            mx[j] = m;
        }
    }
    float mn2 = 0.f;
    #pragma unroll
    for (int j = 0; j < 64; ++j) mn2 = fmaf(mx[j], mx[j], mn2);
    float xnorm = fmaxf(sqrtf(vn2), MINNORM_C);
    float mnorm = fmaxf(sqrtf(mn2), MINNORM_C);
    float z = fminf(xnorm, 1.0f - 1e-7f);                   // artanh clip
    float art = 0.5f * logf((1.0f + z) / (1.0f - z));
    float t = tanhf(mnorm / xnorm * art);
    float scale = (mn2 == 0.f) ? 0.f : (t / mnorm);         // zero_mx branch
    #pragma unroll
    for (int j = 0; j < 64; ++j) mx[j] *= scale;
    float rn2 = 0.f;
    #pragma unroll
    for (int j = 0; j < 64; ++j) rn2 = fmaf(mx[j], mx[j], rn2);
    float rnorm = fmaxf(sqrtf(rn2), MINNORM_C);
    float f = (rnorm > MAXNORM_C) ? (MAXNORM_C / rnorm) : 1.0f;   // proj
    #pragma unroll
    for (int j = 0; j < 64; ++j) mx[j] *= f;
}

// ---------- finalize: two sequential phases so resA/resB never co-live ----------
__global__ __launch_bounds__(256) void finalize_kernel(
    const float* __restrict__ x,
    const float* __restrict__ wt,    // 4 transposed 64x64 matrices
    const float* __restrict__ hb,    // 2 x 65
    float* __restrict__ out) {
    int half = blockIdx.x & 1;                      // uniform -> scalar weight loads
    int group = (blockIdx.x >> 1) * 4 + (threadIdx.x >> 6);
    int lane = threadIdx.x & 63;
    int node = group * 64 + lane;
    bool valid = node < NN;
    int nc = valid ? node : NN - 1;
    float* op = out + (size_t)nc * 128 + half * 64;

    const float* wtA = wt + half * 8192;            // W_pos / W_neg
    const float* wtB = wtA + 4096;                  // W_pos_cc / W_neg_cc
    const float* hbh = hb + half * 65;

    // phase A: proj(mobius_matvec(W, agg)) -> store to out (frees registers)
    {
        float resA[64];
        hyp_mm_proj(op, 1.0f, wtA, resA);
        if (valid) {
            #pragma unroll
            for (int k0 = 0; k0 < 64; k0 += 4)
                *(float4*)(op + k0) = make_float4(resA[k0], resA[k0+1], resA[k0+2], resA[k0+3]);
        }
    }

    // phase B: proj(mobius_add(proj(mobius_matvec(W_cc, x)), hyp_bias))
    float resB[64];
    hyp_mm_proj(x + (size_t)nc * 64, 1.0f, wtB, resB);

    float x2 = 0.f, xy = 0.f;
    #pragma unroll
    for (int j = 0; j < 64; ++j) {
        x2 = fmaf(resB[j], resB[j], x2);
        xy = fmaf(resB[j], hbh[j], xy);
    }
    float y2 = hbh[64];
    float A = 1.f + 2.f * xy + y2;
    float B = 1.f - x2;
    float den = 1.f + 2.f * xy + x2 * y2;
    float dinv = 1.f / fmaxf(den, MINNORM_C);
    float rn2 = 0.f;
    #pragma unroll
    for (int j = 0; j < 64; ++j) {
        float r = (A * resB[j] + B * hbh[j]) * dinv;
        resB[j] = r;
        rn2 = fmaf(r, r, rn2);
    }
    float rnorm = fmaxf(sqrtf(rn2), MINNORM_C);
    float f = (rnorm > MAXNORM_C) ? (MAXNORM_C / rnorm) : 1.0f;

    if (valid) {
        #pragma unroll
        for (int k0 = 0; k0 < 64; k0 += 4) {
            float4 a = *(const float4*)(op + k0);   // resA, L2-hot
            a.x += resB[k0 + 0] * f;
            a.y += resB[k0 + 1] * f;
            a.z += resB[k0 + 2] * f;
            a.w += resB[k0 + 3] * f;
            *(float4*)(op + k0) = a;
        }
    }
}

extern "C" void kernel_launch(void* const* d_in, const int* in_sizes, int n_in,
                              void* d_out, int out_size, void* d_ws, size_t ws_size,
                              hipStream_t stream) {
    const float* x   = (const float*)d_in[0];
    const float* Wp  = (const float*)d_in[1];
    const float* Wpc = (const float*)d_in[2];
    const float* bp  = (const float*)d_in[3];
    const float* Wn  = (const float*)d_in[4];
    const float* Wnc = (const float*)d_in[5];
    const float* bn  = (const float*)d_in[6];
    const int* pei = (const int*)d_in[7];
    const int* nei = (const int*)d_in[8];
    float* out = (float*)d_out;

    int E1 = in_sizes[7] / 2;
    int E2 = in_sizes[8] / 2;
    int tot = E1 + E2;

    // ws layout (4-byte units):
    //   gcnt[NB2] | goffs[NB2] | gcursor[NB2] | pad | ndeg[2NN] | noffs[2NN]
    //   | hb[192] | wt[16384] | packed[tot] | esrc[tot]
    int*   gcnt    = (int*)d_ws;
    int*   goffs   = gcnt + NB2;
    int*   gcursor = goffs + NB2;
    int*   ndeg    = gcursor + NB2 + 2;          // align
    int*   noffs   = ndeg + 2 * NN;
    float* hbp     = (float*)(noffs + 2 * NN);
    float* wt      = hbp + 192;
    int*   packed  = (int*)(wt + 16384);
    int*   esrc    = packed + tot;

    hipMemsetAsync(gcnt, 0, NB2 * sizeof(int), stream);

    prep_transpose<<<64, 256, 0, stream>>>(Wp, Wpc, Wn, Wnc, wt);
    prep_bias<<<1, 64, 0, stream>>>(bp, bn, hbp);

    int nblk = (tot + 8191) / 8192;    // 391
    bucket_count<<<nblk, 256, 0, stream>>>(pei, E1, nei, E2, gcnt);
    bucket_scan<<<1, 256, 0, stream>>>(gcnt, goffs, gcursor);
    bucket_scatter<<<nblk, 256, 0, stream>>>(pei, E1, nei, E2, gcursor, packed);
    node_sort<<<NB2, 256, 0, stream>>>(goffs, gcnt, packed, esrc, ndeg, noffs);

    gather_kernel<<<(2 * NN * 64 + 255) / 256, 256, 0, stream>>>(noffs, ndeg, esrc, x, out);

    int groups = (NN + 63) / 64;                 // 1563
    int blocks = 2 * ((groups + 3) / 4);         // 782
    finalize_kernel<<<blocks, 256, 0, stream>>>(x, wt, hbp, out);
}